// Round 1
// baseline (943.439 us; speedup 1.0000x reference)
//
#include <hip/hip_runtime.h>
#include <math.h>

#define N_NODES 100000
#define N_EDGES 1600000
#define N_GRAPHS 512
#define BN_EPS 1e-5f

// ---------------- workspace layout (bytes) ----------------
constexpr size_t OFF_CNT = 0;                     // int[N]   in-degree counts (excl self-loop)
constexpr size_t OFF_CUR = OFF_CNT + 400000;      // int[N]   scatter cursors (zeroed together with CNT)
constexpr size_t OFF_ROW = OFF_CUR + 400000;      // int[N+1] CSR row starts
constexpr size_t OFF_DIS = OFF_ROW + 400128;      // float[N] rsqrt(deg+1)
constexpr size_t OFF_SC  = OFF_DIS + 400000;      // float[64] BN scale
constexpr size_t OFF_SH  = OFF_SC + 256;          // float[64] BN shift
constexpr size_t OFF_CSR = OFF_SH + 256;          // int[E]   CSR src indices
constexpr size_t OFF_A   = OFF_CSR + 6400000;     // float[N*128] buffer A (xw1, then h1w, 16B aligned)
constexpr size_t OFF_B   = OFF_A + 51200000;      // float[N*128] buffer B (h1, then h2)

// ---------------- CSR build ----------------
__global__ void count_deg(const int* __restrict__ dst, int* __restrict__ cnt) {
    int e = blockIdx.x * blockDim.x + threadIdx.x;
    if (e < N_EDGES) atomicAdd(&cnt[dst[e]], 1);
}

__global__ __launch_bounds__(1024) void scan_deg(const int* __restrict__ cnt,
                                                 int* __restrict__ row_start,
                                                 float* __restrict__ dis) {
    __shared__ int sums[1024];
    int t = threadIdx.x;
    const int CH = (N_NODES + 1023) / 1024; // 98
    int base = t * CH;
    int end = min(base + CH, N_NODES);
    int s = 0;
    for (int i = base; i < end; ++i) s += cnt[i];
    sums[t] = s;
    __syncthreads();
    for (int off = 1; off < 1024; off <<= 1) {
        int add = (t >= off) ? sums[t - off] : 0;
        __syncthreads();
        sums[t] += add;
        __syncthreads();
    }
    int run = (t == 0) ? 0 : sums[t - 1];
    for (int i = base; i < end; ++i) {
        row_start[i] = run;
        int c = cnt[i];
        run += c;
        dis[i] = rsqrtf((float)(c + 1));  // +1 self-loop; deg>0 always
    }
    if (t == 1023) row_start[N_NODES] = sums[1023];
}

__global__ void scatter_csr(const int* __restrict__ src, const int* __restrict__ dst,
                            const int* __restrict__ row_start, int* __restrict__ cursor,
                            int* __restrict__ csr_src) {
    int e = blockIdx.x * blockDim.x + threadIdx.x;
    if (e < N_EDGES) {
        int d = dst[e];
        int pos = row_start[d] + atomicAdd(&cursor[d], 1);
        csr_src[pos] = src[e];
    }
}

// ---------------- GEMM: Y[N,OUTF] = X[N,128] @ W[128,OUTF] ----------------
template <int OUTF>
__global__ __launch_bounds__(256) void gemm_nodes(const float* __restrict__ X,
                                                  const float* __restrict__ W,
                                                  float* __restrict__ Y) {
    constexpr int K = 128;
    constexpr int TN = 64;                 // nodes per block
    constexpr int CPT = 8;                 // cols per thread
    constexpr int CG = OUTF / CPT;         // col groups
    constexpr int NG = 256 / CG;           // node groups
    constexpr int NPT = TN / NG;           // nodes per thread
    __shared__ float sW[K * OUTF];
    __shared__ float sX[TN][K + 1];
    int tid = threadIdx.x;
    int n0 = blockIdx.x * TN;

    for (int i = tid; i < K * OUTF / 4; i += 256)
        ((float4*)sW)[i] = ((const float4*)W)[i];
    for (int i = tid; i < TN * K / 4; i += 256) {
        int idx = i * 4;
        int r = idx / K, c = idx % K;
        int n = n0 + r;
        float4 v = (n < N_NODES) ? ((const float4*)(X + (size_t)n * K))[c >> 2]
                                 : make_float4(0.f, 0.f, 0.f, 0.f);
        sX[r][c] = v.x; sX[r][c + 1] = v.y; sX[r][c + 2] = v.z; sX[r][c + 3] = v.w;
    }
    __syncthreads();

    int cg = tid % CG, ng = tid / CG;
    int c0 = cg * CPT;
    int nb = ng * NPT;
    float acc[NPT][CPT];
#pragma unroll
    for (int i = 0; i < NPT; ++i)
#pragma unroll
        for (int j = 0; j < CPT; ++j) acc[i][j] = 0.f;

#pragma unroll 4
    for (int k = 0; k < K; ++k) {
        float w[CPT];
#pragma unroll
        for (int j = 0; j < CPT; ++j) w[j] = sW[k * OUTF + c0 + j];
#pragma unroll
        for (int i = 0; i < NPT; ++i) {
            float a = sX[nb + i][k];
#pragma unroll
            for (int j = 0; j < CPT; ++j) acc[i][j] = fmaf(a, w[j], acc[i][j]);
        }
    }
#pragma unroll
    for (int i = 0; i < NPT; ++i) {
        int n = n0 + nb + i;
        if (n < N_NODES) {
#pragma unroll
            for (int j = 0; j < CPT; ++j) Y[(size_t)n * OUTF + c0 + j] = acc[i][j];
        }
    }
}

// ---------------- aggregation: out[d] = relu(dis[d]*(sum_in xw[s]*dis[s] + xw[d]*dis[d]) + b) ----
template <int F>
__global__ __launch_bounds__(64) void aggregate(const float* __restrict__ XW,
                                                const int* __restrict__ row_start,
                                                const int* __restrict__ csr_src,
                                                const float* __restrict__ dis,
                                                const float* __restrict__ bias,
                                                float* __restrict__ out) {
    int n = blockIdx.x;
    int lane = threadIdx.x;
    float dn = dis[n];
    int e0 = row_start[n], e1 = row_start[n + 1];
    if (F == 128) {
        float acc0 = 0.f, acc1 = 0.f;
        for (int e = e0; e < e1; ++e) {
            int s = csr_src[e];
            float ds = dis[s];
            float2 v = ((const float2*)(XW + (size_t)s * F))[lane];
            acc0 = fmaf(v.x, ds, acc0);
            acc1 = fmaf(v.y, ds, acc1);
        }
        float2 vn = ((const float2*)(XW + (size_t)n * F))[lane];
        acc0 = fmaf(vn.x, dn, acc0);
        acc1 = fmaf(vn.y, dn, acc1);
        acc0 = fmaf(acc0, dn, bias[2 * lane]);
        acc1 = fmaf(acc1, dn, bias[2 * lane + 1]);
        float2 o;
        o.x = fmaxf(acc0, 0.f);
        o.y = fmaxf(acc1, 0.f);
        ((float2*)(out + (size_t)n * F))[lane] = o;
    } else {
        float acc = 0.f;
        for (int e = e0; e < e1; ++e) {
            int s = csr_src[e];
            acc = fmaf(XW[(size_t)s * F + lane], dis[s], acc);
        }
        acc = fmaf(XW[(size_t)n * F + lane], dn, acc);
        acc = fmaf(acc, dn, bias[lane]);
        out[(size_t)n * F + lane] = fmaxf(acc, 0.f);
    }
}

// ---------------- pooling: pooled[g] = sum over nodes with batch==g (batch sorted) ----------------
__global__ __launch_bounds__(64) void pool_graphs(const float* __restrict__ H,
                                                  const int* __restrict__ batch,
                                                  float* __restrict__ pooled) {
    int g = blockIdx.x;
    int lane = threadIdx.x;
    int lo = 0, hi = N_NODES;
    while (lo < hi) { int mid = (lo + hi) >> 1; if (batch[mid] < g) lo = mid + 1; else hi = mid; }
    int start = lo;
    hi = N_NODES;
    while (lo < hi) { int mid = (lo + hi) >> 1; if (batch[mid] < g + 1) lo = mid + 1; else hi = mid; }
    int end = lo;
    float acc = 0.f;
    for (int i = start; i < end; ++i) acc += H[(size_t)i * 64 + lane];
    pooled[g * 64 + lane] = acc;
}

// ---------------- BN batch stats -> scale/shift ----------------
__global__ __launch_bounds__(64) void bn_stats(const float* __restrict__ pooled,
                                               const float* __restrict__ gamma,
                                               const float* __restrict__ beta,
                                               float* __restrict__ scale,
                                               float* __restrict__ shift) {
    int f = threadIdx.x;
    float s = 0.f, s2 = 0.f;
    for (int g = 0; g < N_GRAPHS; ++g) {
        float v = pooled[g * 64 + f];
        s += v;
        s2 = fmaf(v, v, s2);
    }
    float mean = s * (1.0f / N_GRAPHS);
    float var = s2 * (1.0f / N_GRAPHS) - mean * mean;
    float istd = rsqrtf(var + BN_EPS);
    float sc = gamma[f] * istd;
    scale[f] = sc;
    shift[f] = beta[f] - mean * sc;
}

// ---------------- head: out[g] = relu(xn @ Wo1 + bo1) @ Wo2 + bo2 ----------------
__global__ __launch_bounds__(256) void head(const float* __restrict__ pooled,
                                            const float* __restrict__ scale,
                                            const float* __restrict__ shift,
                                            const float* __restrict__ Wo1,
                                            const float* __restrict__ bo1,
                                            const float* __restrict__ Wo2,
                                            const float* __restrict__ bo2,
                                            float* __restrict__ out) {
    __shared__ float sW1[64 * 24];
    __shared__ float sW2[24];
    __shared__ float sb1[24];
    __shared__ float ssc[64];
    __shared__ float ssh[64];
    int tid = threadIdx.x;
    for (int i = tid; i < 64 * 24; i += 256) sW1[i] = Wo1[i];
    if (tid < 24) { sW2[tid] = Wo2[tid]; sb1[tid] = bo1[tid]; }
    if (tid < 64) { ssc[tid] = scale[tid]; ssh[tid] = shift[tid]; }
    __syncthreads();
    int g = blockIdx.x * 256 + tid;
    if (g >= N_GRAPHS) return;
    float xn[64];
    const float* pr = pooled + g * 64;
#pragma unroll
    for (int j = 0; j < 64; ++j) xn[j] = fmaf(pr[j], ssc[j], ssh[j]);
    float o = bo2[0];
#pragma unroll 4
    for (int k = 0; k < 24; ++k) {
        float h = sb1[k];
#pragma unroll
        for (int j = 0; j < 64; ++j) h = fmaf(xn[j], sW1[j * 24 + k], h);
        o = fmaf(fmaxf(h, 0.f), sW2[k], o);
    }
    out[g] = o;
}

extern "C" void kernel_launch(void* const* d_in, const int* in_sizes, int n_in,
                              void* d_out, int out_size, void* d_ws, size_t ws_size,
                              hipStream_t stream) {
    const float* x     = (const float*)d_in[0];
    const int*   ei    = (const int*)d_in[1];   // [2,E]: first E = src, next E = dst
    const int*   batch = (const int*)d_in[2];
    const float* W1    = (const float*)d_in[3];
    const float* b1    = (const float*)d_in[4];
    const float* W2    = (const float*)d_in[5];
    const float* b2    = (const float*)d_in[6];
    const float* gamma = (const float*)d_in[7];
    const float* beta  = (const float*)d_in[8];
    const float* Wo1   = (const float*)d_in[9];
    const float* bo1   = (const float*)d_in[10];
    const float* Wo2   = (const float*)d_in[11];
    const float* bo2   = (const float*)d_in[12];
    float* out = (float*)d_out;               // [512] out, then [512*64] h(=pooled)
    char* ws = (char*)d_ws;

    const int* srcv = ei;
    const int* dstv = ei + N_EDGES;
    int*   cnt      = (int*)(ws + OFF_CNT);
    int*   cursor   = (int*)(ws + OFF_CUR);
    int*   row_start= (int*)(ws + OFF_ROW);
    float* dis      = (float*)(ws + OFF_DIS);
    float* scale    = (float*)(ws + OFF_SC);
    float* shift    = (float*)(ws + OFF_SH);
    int*   csr_src  = (int*)(ws + OFF_CSR);
    float* bufA     = (float*)(ws + OFF_A);
    float* bufB     = (float*)(ws + OFF_B);
    float* pooled   = out + N_GRAPHS;         // h output region, also used downstream

    // zero counters (cnt + cursor are contiguous)
    hipMemsetAsync(ws + OFF_CNT, 0, 800000, stream);

    int eblocks = (N_EDGES + 255) / 256;
    count_deg<<<eblocks, 256, 0, stream>>>(dstv, cnt);
    scan_deg<<<1, 1024, 0, stream>>>(cnt, row_start, dis);
    scatter_csr<<<eblocks, 256, 0, stream>>>(srcv, dstv, row_start, cursor, csr_src);

    int gblocks = (N_NODES + 63) / 64;
    gemm_nodes<128><<<gblocks, 256, 0, stream>>>(x, W1, bufA);
    aggregate<128><<<N_NODES, 64, 0, stream>>>(bufA, row_start, csr_src, dis, b1, bufB);
    gemm_nodes<64><<<gblocks, 256, 0, stream>>>(bufB, W2, bufA);
    aggregate<64><<<N_NODES, 64, 0, stream>>>(bufA, row_start, csr_src, dis, b2, bufB);

    pool_graphs<<<N_GRAPHS, 64, 0, stream>>>(bufB, batch, pooled);
    bn_stats<<<1, 64, 0, stream>>>(pooled, gamma, beta, scale, shift);
    head<<<2, 256, 0, stream>>>(pooled, scale, shift, Wo1, bo1, Wo2, bo2, out);
}

// Round 2
// 725.381 us; speedup vs baseline: 1.3006x; 1.3006x over previous
//
#include <hip/hip_runtime.h>
#include <math.h>

#define N_NODES 100000
#define N_EDGES 1600000
#define N_GRAPHS 512
#define BN_EPS 1e-5f

#define SCAN_BLOCKS ((N_NODES + 1023) / 1024)   // 98

// ---------------- workspace layout (bytes) ----------------
constexpr size_t OFF_CNT = 0;                     // int[N]   in-degree counts (excl self-loop)
constexpr size_t OFF_CUR = OFF_CNT + 400000;      // int[N]   scatter cursors (zeroed together with CNT)
constexpr size_t OFF_ROW = OFF_CUR + 400000;      // int[N+1] CSR row starts
constexpr size_t OFF_DIS = OFF_ROW + 400128;      // float[N] rsqrt(deg+1)
constexpr size_t OFF_SC  = OFF_DIS + 400000;      // float[64] BN scale
constexpr size_t OFF_SH  = OFF_SC + 256;          // float[64] BN shift
constexpr size_t OFF_BS  = OFF_SH + 256;          // int[128] scanned block sums
constexpr size_t OFF_CSR = OFF_BS + 512;          // int[E]   CSR src indices
constexpr size_t OFF_A   = OFF_CSR + 6400000;     // float[N*128] buffer A (xw1, then h1w)
constexpr size_t OFF_B   = OFF_A + 51200000;      // float[N*128] buffer B (h1, then h2)

// ---------------- CSR build ----------------
__global__ void count_deg(const int* __restrict__ dst, int* __restrict__ cnt) {
    int e = blockIdx.x * blockDim.x + threadIdx.x;
    if (e < N_EDGES) atomicAdd(&cnt[dst[e]], 1);
}

// phase 1: per-block inclusive scan of cnt into row_start; block totals out
__global__ __launch_bounds__(1024) void scan_block(const int* __restrict__ cnt,
                                                   int* __restrict__ row_start,
                                                   int* __restrict__ block_sums) {
    __shared__ int tmp[1024];
    int t = threadIdx.x;
    int i = blockIdx.x * 1024 + t;
    int v = (i < N_NODES) ? cnt[i] : 0;
    tmp[t] = v;
    __syncthreads();
    for (int off = 1; off < 1024; off <<= 1) {
        int add = (t >= off) ? tmp[t - off] : 0;
        __syncthreads();
        tmp[t] += add;
        __syncthreads();
    }
    if (i < N_NODES) row_start[i] = tmp[t];      // inclusive, block-local
    if (t == 1023) block_sums[blockIdx.x] = tmp[1023];
}

// phase 2: inclusive scan of the (<=128) block totals
__global__ __launch_bounds__(128) void scan_tops(int* __restrict__ block_sums) {
    __shared__ int tmp[128];
    int t = threadIdx.x;
    tmp[t] = (t < SCAN_BLOCKS) ? block_sums[t] : 0;
    __syncthreads();
    for (int off = 1; off < 128; off <<= 1) {
        int add = (t >= off) ? tmp[t - off] : 0;
        __syncthreads();
        tmp[t] += add;
        __syncthreads();
    }
    block_sums[t] = tmp[t];
}

// phase 3: convert to global exclusive scan; fuse dis = rsqrt(deg+1)
__global__ __launch_bounds__(1024) void scan_final(const int* __restrict__ cnt,
                                                   const int* __restrict__ block_sums,
                                                   int* __restrict__ row_start,
                                                   float* __restrict__ dis) {
    int t = threadIdx.x;
    int b = blockIdx.x;
    int i = b * 1024 + t;
    if (i < N_NODES) {
        int off = (b == 0) ? 0 : block_sums[b - 1];
        int c = cnt[i];
        row_start[i] = row_start[i] - c + off;   // exclusive
        dis[i] = rsqrtf((float)(c + 1));         // +1 self-loop
    }
    if (i == 0) row_start[N_NODES] = N_EDGES;
}

__global__ void scatter_csr(const int* __restrict__ src, const int* __restrict__ dst,
                            const int* __restrict__ row_start, int* __restrict__ cursor,
                            int* __restrict__ csr_src) {
    int e = blockIdx.x * blockDim.x + threadIdx.x;
    if (e < N_EDGES) {
        int d = dst[e];
        int pos = row_start[d] + atomicAdd(&cursor[d], 1);
        csr_src[pos] = src[e];
    }
}

// ---------------- GEMM: Y[N,OUTF] = X[N,128] @ W[128,OUTF] ----------------
template <int OUTF>
__global__ __launch_bounds__(256) void gemm_nodes(const float* __restrict__ X,
                                                  const float* __restrict__ W,
                                                  float* __restrict__ Y) {
    constexpr int K = 128;
    constexpr int TN = 64;                 // nodes per block
    constexpr int CPT = 8;                 // cols per thread
    constexpr int CG = OUTF / CPT;         // col groups
    constexpr int NG = 256 / CG;           // node groups
    constexpr int NPT = TN / NG;           // nodes per thread
    __shared__ float sW[K * OUTF];
    __shared__ float sX[TN][K + 1];
    int tid = threadIdx.x;
    int n0 = blockIdx.x * TN;

    for (int i = tid; i < K * OUTF / 4; i += 256)
        ((float4*)sW)[i] = ((const float4*)W)[i];
    for (int i = tid; i < TN * K / 4; i += 256) {
        int idx = i * 4;
        int r = idx / K, c = idx % K;
        int n = n0 + r;
        float4 v = (n < N_NODES) ? ((const float4*)(X + (size_t)n * K))[c >> 2]
                                 : make_float4(0.f, 0.f, 0.f, 0.f);
        sX[r][c] = v.x; sX[r][c + 1] = v.y; sX[r][c + 2] = v.z; sX[r][c + 3] = v.w;
    }
    __syncthreads();

    int cg = tid % CG, ng = tid / CG;
    int c0 = cg * CPT;
    int nb = ng * NPT;
    float acc[NPT][CPT];
#pragma unroll
    for (int i = 0; i < NPT; ++i)
#pragma unroll
        for (int j = 0; j < CPT; ++j) acc[i][j] = 0.f;

#pragma unroll 4
    for (int k = 0; k < K; ++k) {
        float w[CPT];
#pragma unroll
        for (int j = 0; j < CPT; ++j) w[j] = sW[k * OUTF + c0 + j];
#pragma unroll
        for (int i = 0; i < NPT; ++i) {
            float a = sX[nb + i][k];
#pragma unroll
            for (int j = 0; j < CPT; ++j) acc[i][j] = fmaf(a, w[j], acc[i][j]);
        }
    }
#pragma unroll
    for (int i = 0; i < NPT; ++i) {
        int n = n0 + nb + i;
        if (n < N_NODES) {
#pragma unroll
            for (int j = 0; j < CPT; ++j) Y[(size_t)n * OUTF + c0 + j] = acc[i][j];
        }
    }
}

// ---------------- aggregation: out[d] = relu(dis[d]*(sum_in xw[s]*dis[s] + xw[d]*dis[d]) + b) ----
template <int F>
__global__ __launch_bounds__(64) void aggregate(const float* __restrict__ XW,
                                                const int* __restrict__ row_start,
                                                const int* __restrict__ csr_src,
                                                const float* __restrict__ dis,
                                                const float* __restrict__ bias,
                                                float* __restrict__ out) {
    int n = blockIdx.x;
    int lane = threadIdx.x;
    float dn = dis[n];
    int e0 = row_start[n], e1 = row_start[n + 1];
    if (F == 128) {
        float acc0 = 0.f, acc1 = 0.f;
        for (int e = e0; e < e1; ++e) {
            int s = csr_src[e];
            float ds = dis[s];
            float2 v = ((const float2*)(XW + (size_t)s * F))[lane];
            acc0 = fmaf(v.x, ds, acc0);
            acc1 = fmaf(v.y, ds, acc1);
        }
        float2 vn = ((const float2*)(XW + (size_t)n * F))[lane];
        acc0 = fmaf(vn.x, dn, acc0);
        acc1 = fmaf(vn.y, dn, acc1);
        acc0 = fmaf(acc0, dn, bias[2 * lane]);
        acc1 = fmaf(acc1, dn, bias[2 * lane + 1]);
        float2 o;
        o.x = fmaxf(acc0, 0.f);
        o.y = fmaxf(acc1, 0.f);
        ((float2*)(out + (size_t)n * F))[lane] = o;
    } else {
        float acc = 0.f;
        for (int e = e0; e < e1; ++e) {
            int s = csr_src[e];
            acc = fmaf(XW[(size_t)s * F + lane], dis[s], acc);
        }
        acc = fmaf(XW[(size_t)n * F + lane], dn, acc);
        acc = fmaf(acc, dn, bias[lane]);
        out[(size_t)n * F + lane] = fmaxf(acc, 0.f);
    }
}

// ---------------- pooling: pooled[g] = sum over nodes with batch==g (batch sorted) ----------------
__global__ __launch_bounds__(64) void pool_graphs(const float* __restrict__ H,
                                                  const int* __restrict__ batch,
                                                  float* __restrict__ pooled) {
    int g = blockIdx.x;
    int lane = threadIdx.x;
    int lo = 0, hi = N_NODES;
    while (lo < hi) { int mid = (lo + hi) >> 1; if (batch[mid] < g) lo = mid + 1; else hi = mid; }
    int start = lo;
    hi = N_NODES;
    while (lo < hi) { int mid = (lo + hi) >> 1; if (batch[mid] < g + 1) lo = mid + 1; else hi = mid; }
    int end = lo;
    float acc = 0.f;
    for (int i = start; i < end; ++i) acc += H[(size_t)i * 64 + lane];
    pooled[g * 64 + lane] = acc;
}

// ---------------- BN batch stats -> scale/shift ----------------
__global__ __launch_bounds__(64) void bn_stats(const float* __restrict__ pooled,
                                               const float* __restrict__ gamma,
                                               const float* __restrict__ beta,
                                               float* __restrict__ scale,
                                               float* __restrict__ shift) {
    int f = threadIdx.x;
    float s = 0.f, s2 = 0.f;
    for (int g = 0; g < N_GRAPHS; ++g) {
        float v = pooled[g * 64 + f];
        s += v;
        s2 = fmaf(v, v, s2);
    }
    float mean = s * (1.0f / N_GRAPHS);
    float var = s2 * (1.0f / N_GRAPHS) - mean * mean;
    float istd = rsqrtf(var + BN_EPS);
    float sc = gamma[f] * istd;
    scale[f] = sc;
    shift[f] = beta[f] - mean * sc;
}

// ---------------- head: out[g] = relu(xn @ Wo1 + bo1) @ Wo2 + bo2 ----------------
__global__ __launch_bounds__(256) void head(const float* __restrict__ pooled,
                                            const float* __restrict__ scale,
                                            const float* __restrict__ shift,
                                            const float* __restrict__ Wo1,
                                            const float* __restrict__ bo1,
                                            const float* __restrict__ Wo2,
                                            const float* __restrict__ bo2,
                                            float* __restrict__ out) {
    __shared__ float sW1[64 * 24];
    __shared__ float sW2[24];
    __shared__ float sb1[24];
    __shared__ float ssc[64];
    __shared__ float ssh[64];
    int tid = threadIdx.x;
    for (int i = tid; i < 64 * 24; i += 256) sW1[i] = Wo1[i];
    if (tid < 24) { sW2[tid] = Wo2[tid]; sb1[tid] = bo1[tid]; }
    if (tid < 64) { ssc[tid] = scale[tid]; ssh[tid] = shift[tid]; }
    __syncthreads();
    int g = blockIdx.x * 256 + tid;
    if (g >= N_GRAPHS) return;
    float xn[64];
    const float* pr = pooled + g * 64;
#pragma unroll
    for (int j = 0; j < 64; ++j) xn[j] = fmaf(pr[j], ssc[j], ssh[j]);
    float o = bo2[0];
#pragma unroll 4
    for (int k = 0; k < 24; ++k) {
        float h = sb1[k];
#pragma unroll
        for (int j = 0; j < 64; ++j) h = fmaf(xn[j], sW1[j * 24 + k], h);
        o = fmaf(fmaxf(h, 0.f), sW2[k], o);
    }
    out[g] = o;
}

extern "C" void kernel_launch(void* const* d_in, const int* in_sizes, int n_in,
                              void* d_out, int out_size, void* d_ws, size_t ws_size,
                              hipStream_t stream) {
    const float* x     = (const float*)d_in[0];
    const int*   ei    = (const int*)d_in[1];   // [2,E]: first E = src, next E = dst
    const int*   batch = (const int*)d_in[2];
    const float* W1    = (const float*)d_in[3];
    const float* b1    = (const float*)d_in[4];
    const float* W2    = (const float*)d_in[5];
    const float* b2    = (const float*)d_in[6];
    const float* gamma = (const float*)d_in[7];
    const float* beta  = (const float*)d_in[8];
    const float* Wo1   = (const float*)d_in[9];
    const float* bo1   = (const float*)d_in[10];
    const float* Wo2   = (const float*)d_in[11];
    const float* bo2   = (const float*)d_in[12];
    float* out = (float*)d_out;               // [512] out, then [512*64] h(=pooled)
    char* ws = (char*)d_ws;

    const int* srcv = ei;
    const int* dstv = ei + N_EDGES;
    int*   cnt      = (int*)(ws + OFF_CNT);
    int*   cursor   = (int*)(ws + OFF_CUR);
    int*   row_start= (int*)(ws + OFF_ROW);
    float* dis      = (float*)(ws + OFF_DIS);
    float* scale    = (float*)(ws + OFF_SC);
    float* shift    = (float*)(ws + OFF_SH);
    int*   bsums    = (int*)(ws + OFF_BS);
    int*   csr_src  = (int*)(ws + OFF_CSR);
    float* bufA     = (float*)(ws + OFF_A);
    float* bufB     = (float*)(ws + OFF_B);
    float* pooled   = out + N_GRAPHS;         // h output region, also used downstream

    // zero counters (cnt + cursor are contiguous)
    hipMemsetAsync(ws + OFF_CNT, 0, 800000, stream);

    int eblocks = (N_EDGES + 255) / 256;
    count_deg<<<eblocks, 256, 0, stream>>>(dstv, cnt);
    scan_block<<<SCAN_BLOCKS, 1024, 0, stream>>>(cnt, row_start, bsums);
    scan_tops<<<1, 128, 0, stream>>>(bsums);
    scan_final<<<SCAN_BLOCKS, 1024, 0, stream>>>(cnt, bsums, row_start, dis);
    scatter_csr<<<eblocks, 256, 0, stream>>>(srcv, dstv, row_start, cursor, csr_src);

    int gblocks = (N_NODES + 63) / 64;
    gemm_nodes<128><<<gblocks, 256, 0, stream>>>(x, W1, bufA);
    aggregate<128><<<N_NODES, 64, 0, stream>>>(bufA, row_start, csr_src, dis, b1, bufB);
    gemm_nodes<64><<<gblocks, 256, 0, stream>>>(bufB, W2, bufA);
    aggregate<64><<<N_NODES, 64, 0, stream>>>(bufA, row_start, csr_src, dis, b2, bufB);

    pool_graphs<<<N_GRAPHS, 64, 0, stream>>>(bufB, batch, pooled);
    bn_stats<<<1, 64, 0, stream>>>(pooled, gamma, beta, scale, shift);
    head<<<2, 256, 0, stream>>>(pooled, scale, shift, Wo1, bo1, Wo2, bo2, out);
}

// Round 3
// 710.008 us; speedup vs baseline: 1.3288x; 1.0217x over previous
//
#include <hip/hip_runtime.h>
#include <math.h>

#define N_NODES 100000
#define N_EDGES 1600000
#define N_GRAPHS 512
#define BN_EPS 1e-5f

#define SCAN_BLOCKS ((N_NODES + 1023) / 1024)   // 98

typedef unsigned int uint;
typedef unsigned short ushort;

// ---------------- workspace layout (bytes) ----------------
constexpr size_t OFF_CNT = 0;                     // int[N]   in-degree counts (excl self-loop)
constexpr size_t OFF_CUR = OFF_CNT + 400000;      // int[N]   scatter cursors
constexpr size_t OFF_ROW = OFF_CUR + 400000;      // int[N+1] CSR row starts
constexpr size_t OFF_DIS = OFF_ROW + 400128;      // float[N] rsqrt(deg+1)
constexpr size_t OFF_SC  = OFF_DIS + 400000;      // float[64] BN scale
constexpr size_t OFF_SH  = OFF_SC + 256;          // float[64] BN shift
constexpr size_t OFF_BS  = OFF_SH + 256;          // int[128] scanned block sums
constexpr size_t OFF_CSR = OFF_BS + 512;          // int[E]   CSR src indices
constexpr size_t OFF_A   = OFF_CSR + 6400000;     // bf16[N*128] M = (xw*dis) rows (gather source)
constexpr size_t OFF_B   = OFF_A + 25600000;      // float[N*128] buffer B (h1, then h2)

__device__ __forceinline__ ushort f2bf(float f) {
    uint u = __float_as_uint(f);
    uint r = (u + 0x7fffu + ((u >> 16) & 1u)) >> 16;  // round-to-nearest-even
    return (ushort)r;
}

// ---------------- CSR build ----------------
__global__ void count_deg(const int* __restrict__ dst, int* __restrict__ cnt) {
    int e = blockIdx.x * blockDim.x + threadIdx.x;
    if (e < N_EDGES) atomicAdd(&cnt[dst[e]], 1);
}

__global__ __launch_bounds__(1024) void scan_block(const int* __restrict__ cnt,
                                                   int* __restrict__ row_start,
                                                   int* __restrict__ block_sums) {
    __shared__ int tmp[1024];
    int t = threadIdx.x;
    int i = blockIdx.x * 1024 + t;
    int v = (i < N_NODES) ? cnt[i] : 0;
    tmp[t] = v;
    __syncthreads();
    for (int off = 1; off < 1024; off <<= 1) {
        int add = (t >= off) ? tmp[t - off] : 0;
        __syncthreads();
        tmp[t] += add;
        __syncthreads();
    }
    if (i < N_NODES) row_start[i] = tmp[t];      // inclusive, block-local
    if (t == 1023) block_sums[blockIdx.x] = tmp[1023];
}

__global__ __launch_bounds__(128) void scan_tops(int* __restrict__ block_sums) {
    __shared__ int tmp[128];
    int t = threadIdx.x;
    tmp[t] = (t < SCAN_BLOCKS) ? block_sums[t] : 0;
    __syncthreads();
    for (int off = 1; off < 128; off <<= 1) {
        int add = (t >= off) ? tmp[t - off] : 0;
        __syncthreads();
        tmp[t] += add;
        __syncthreads();
    }
    block_sums[t] = tmp[t];
}

__global__ __launch_bounds__(1024) void scan_final(const int* __restrict__ cnt,
                                                   const int* __restrict__ block_sums,
                                                   int* __restrict__ row_start,
                                                   float* __restrict__ dis) {
    int t = threadIdx.x;
    int b = blockIdx.x;
    int i = b * 1024 + t;
    if (i < N_NODES) {
        int off = (b == 0) ? 0 : block_sums[b - 1];
        int c = cnt[i];
        row_start[i] = row_start[i] - c + off;   // exclusive
        dis[i] = rsqrtf((float)(c + 1));         // +1 self-loop
    }
    if (i == 0) row_start[N_NODES] = N_EDGES;
}

__global__ void scatter_csr(const int* __restrict__ src, const int* __restrict__ dst,
                            const int* __restrict__ row_start, int* __restrict__ cursor,
                            int* __restrict__ csr_src) {
    int e = blockIdx.x * blockDim.x + threadIdx.x;
    if (e < N_EDGES) {
        int d = dst[e];
        int pos = row_start[d] + atomicAdd(&cursor[d], 1);
        csr_src[pos] = src[e];
    }
}

// ---------------- GEMM: Y[n, :] = bf16( dis[n] * (X[n,:] @ W) )  ----------------
template <int OUTF>
__global__ __launch_bounds__(256) void gemm_nodes(const float* __restrict__ X,
                                                  const float* __restrict__ W,
                                                  const float* __restrict__ dis,
                                                  ushort* __restrict__ Y) {
    constexpr int K = 128;
    constexpr int TN = 64;                 // nodes per block
    constexpr int CPT = 8;                 // cols per thread
    constexpr int CG = OUTF / CPT;         // col groups
    constexpr int NG = 256 / CG;           // node groups
    constexpr int NPT = TN / NG;           // nodes per thread
    __shared__ float sW[K * OUTF];
    __shared__ float sX[TN][K + 1];
    int tid = threadIdx.x;
    int n0 = blockIdx.x * TN;

    for (int i = tid; i < K * OUTF / 4; i += 256)
        ((float4*)sW)[i] = ((const float4*)W)[i];
    for (int i = tid; i < TN * K / 4; i += 256) {
        int idx = i * 4;
        int r = idx / K, c = idx % K;
        int n = n0 + r;
        float4 v = (n < N_NODES) ? ((const float4*)(X + (size_t)n * K))[c >> 2]
                                 : make_float4(0.f, 0.f, 0.f, 0.f);
        sX[r][c] = v.x; sX[r][c + 1] = v.y; sX[r][c + 2] = v.z; sX[r][c + 3] = v.w;
    }
    __syncthreads();

    int cg = tid % CG, ng = tid / CG;
    int c0 = cg * CPT;
    int nb = ng * NPT;
    float acc[NPT][CPT];
#pragma unroll
    for (int i = 0; i < NPT; ++i)
#pragma unroll
        for (int j = 0; j < CPT; ++j) acc[i][j] = 0.f;

#pragma unroll 4
    for (int k = 0; k < K; ++k) {
        float w[CPT];
#pragma unroll
        for (int j = 0; j < CPT; ++j) w[j] = sW[k * OUTF + c0 + j];
#pragma unroll
        for (int i = 0; i < NPT; ++i) {
            float a = sX[nb + i][k];
#pragma unroll
            for (int j = 0; j < CPT; ++j) acc[i][j] = fmaf(a, w[j], acc[i][j]);
        }
    }
#pragma unroll
    for (int i = 0; i < NPT; ++i) {
        int n = n0 + nb + i;
        if (n < N_NODES) {
            float dn = dis[n];
            uint4 pk;
            uint* pu = (uint*)&pk;
#pragma unroll
            for (int j = 0; j < 4; ++j) {
                uint lo = f2bf(acc[i][2 * j] * dn);
                uint hi = f2bf(acc[i][2 * j + 1] * dn);
                pu[j] = lo | (hi << 16);
            }
            ((uint4*)(Y + (size_t)n * OUTF))[cg] = pk;
        }
    }
}

// ---- aggregation: out[d] = relu(dis[d]*(sum_in M[s] + M[d]) + b), M = bf16(xw*dis) ----
template <int F>
__global__ __launch_bounds__(64) void aggregate(const ushort* __restrict__ M,
                                                const int* __restrict__ row_start,
                                                const int* __restrict__ csr_src,
                                                const float* __restrict__ dis,
                                                const float* __restrict__ bias,
                                                float* __restrict__ out) {
    int n = blockIdx.x;
    int lane = threadIdx.x;
    float dn = dis[n];
    int e0 = row_start[n], e1 = row_start[n + 1];
    if (F == 128) {
        const uint* rows = (const uint*)M;       // 64 uints per row
        float acc0 = 0.f, acc1 = 0.f;
        uint u = rows[(size_t)n * 64 + lane];    // self-loop term
        acc0 += __uint_as_float(u << 16);
        acc1 += __uint_as_float(u & 0xffff0000u);
        for (int e = e0; e < e1; ++e) {
            int s = csr_src[e];
            uint v = rows[(size_t)s * 64 + lane];
            acc0 += __uint_as_float(v << 16);
            acc1 += __uint_as_float(v & 0xffff0000u);
        }
        acc0 = fmaf(acc0, dn, bias[2 * lane]);
        acc1 = fmaf(acc1, dn, bias[2 * lane + 1]);
        float2 o;
        o.x = fmaxf(acc0, 0.f);
        o.y = fmaxf(acc1, 0.f);
        ((float2*)(out + (size_t)n * F))[lane] = o;
    } else {
        float acc = __uint_as_float(((uint)M[(size_t)n * F + lane]) << 16);
        for (int e = e0; e < e1; ++e) {
            int s = csr_src[e];
            acc += __uint_as_float(((uint)M[(size_t)s * F + lane]) << 16);
        }
        acc = fmaf(acc, dn, bias[lane]);
        out[(size_t)n * F + lane] = fmaxf(acc, 0.f);
    }
}

// ---------------- pooling ----------------
__global__ __launch_bounds__(64) void pool_graphs(const float* __restrict__ H,
                                                  const int* __restrict__ batch,
                                                  float* __restrict__ pooled) {
    int g = blockIdx.x;
    int lane = threadIdx.x;
    int lo = 0, hi = N_NODES;
    while (lo < hi) { int mid = (lo + hi) >> 1; if (batch[mid] < g) lo = mid + 1; else hi = mid; }
    int start = lo;
    hi = N_NODES;
    while (lo < hi) { int mid = (lo + hi) >> 1; if (batch[mid] < g + 1) lo = mid + 1; else hi = mid; }
    int end = lo;
    float acc = 0.f;
    for (int i = start; i < end; ++i) acc += H[(size_t)i * 64 + lane];
    pooled[g * 64 + lane] = acc;
}

// ---------------- BN batch stats -> scale/shift ----------------
__global__ __launch_bounds__(64) void bn_stats(const float* __restrict__ pooled,
                                               const float* __restrict__ gamma,
                                               const float* __restrict__ beta,
                                               float* __restrict__ scale,
                                               float* __restrict__ shift) {
    int f = threadIdx.x;
    float s = 0.f, s2 = 0.f;
    for (int g = 0; g < N_GRAPHS; ++g) {
        float v = pooled[g * 64 + f];
        s += v;
        s2 = fmaf(v, v, s2);
    }
    float mean = s * (1.0f / N_GRAPHS);
    float var = s2 * (1.0f / N_GRAPHS) - mean * mean;
    float istd = rsqrtf(var + BN_EPS);
    float sc = gamma[f] * istd;
    scale[f] = sc;
    shift[f] = beta[f] - mean * sc;
}

// ---------------- head ----------------
__global__ __launch_bounds__(256) void head(const float* __restrict__ pooled,
                                            const float* __restrict__ scale,
                                            const float* __restrict__ shift,
                                            const float* __restrict__ Wo1,
                                            const float* __restrict__ bo1,
                                            const float* __restrict__ Wo2,
                                            const float* __restrict__ bo2,
                                            float* __restrict__ out) {
    __shared__ float sW1[64 * 24];
    __shared__ float sW2[24];
    __shared__ float sb1[24];
    __shared__ float ssc[64];
    __shared__ float ssh[64];
    int tid = threadIdx.x;
    for (int i = tid; i < 64 * 24; i += 256) sW1[i] = Wo1[i];
    if (tid < 24) { sW2[tid] = Wo2[tid]; sb1[tid] = bo1[tid]; }
    if (tid < 64) { ssc[tid] = scale[tid]; ssh[tid] = shift[tid]; }
    __syncthreads();
    int g = blockIdx.x * 256 + tid;
    if (g >= N_GRAPHS) return;
    float xn[64];
    const float* pr = pooled + g * 64;
#pragma unroll
    for (int j = 0; j < 64; ++j) xn[j] = fmaf(pr[j], ssc[j], ssh[j]);
    float o = bo2[0];
#pragma unroll 4
    for (int k = 0; k < 24; ++k) {
        float h = sb1[k];
#pragma unroll
        for (int j = 0; j < 64; ++j) h = fmaf(xn[j], sW1[j * 24 + k], h);
        o = fmaf(fmaxf(h, 0.f), sW2[k], o);
    }
    out[g] = o;
}

extern "C" void kernel_launch(void* const* d_in, const int* in_sizes, int n_in,
                              void* d_out, int out_size, void* d_ws, size_t ws_size,
                              hipStream_t stream) {
    const float* x     = (const float*)d_in[0];
    const int*   ei    = (const int*)d_in[1];   // [2,E]: first E = src, next E = dst
    const int*   batch = (const int*)d_in[2];
    const float* W1    = (const float*)d_in[3];
    const float* b1    = (const float*)d_in[4];
    const float* W2    = (const float*)d_in[5];
    const float* b2    = (const float*)d_in[6];
    const float* gamma = (const float*)d_in[7];
    const float* beta  = (const float*)d_in[8];
    const float* Wo1   = (const float*)d_in[9];
    const float* bo1   = (const float*)d_in[10];
    const float* Wo2   = (const float*)d_in[11];
    const float* bo2   = (const float*)d_in[12];
    float* out = (float*)d_out;               // [512] out, then [512*64] h(=pooled)
    char* ws = (char*)d_ws;

    const int* srcv = ei;
    const int* dstv = ei + N_EDGES;
    int*   cnt      = (int*)(ws + OFF_CNT);
    int*   cursor   = (int*)(ws + OFF_CUR);
    int*   row_start= (int*)(ws + OFF_ROW);
    float* dis      = (float*)(ws + OFF_DIS);
    float* scale    = (float*)(ws + OFF_SC);
    float* shift    = (float*)(ws + OFF_SH);
    int*   bsums    = (int*)(ws + OFF_BS);
    int*   csr_src  = (int*)(ws + OFF_CSR);
    ushort* bufA    = (ushort*)(ws + OFF_A);  // bf16 message rows
    float* bufB     = (float*)(ws + OFF_B);
    float* pooled   = out + N_GRAPHS;         // h output region, also used downstream

    hipMemsetAsync(ws + OFF_CNT, 0, 800000, stream);

    int eblocks = (N_EDGES + 255) / 256;
    count_deg<<<eblocks, 256, 0, stream>>>(dstv, cnt);
    scan_block<<<SCAN_BLOCKS, 1024, 0, stream>>>(cnt, row_start, bsums);
    scan_tops<<<1, 128, 0, stream>>>(bsums);
    scan_final<<<SCAN_BLOCKS, 1024, 0, stream>>>(cnt, bsums, row_start, dis);
    scatter_csr<<<eblocks, 256, 0, stream>>>(srcv, dstv, row_start, cursor, csr_src);

    int gblocks = (N_NODES + 63) / 64;
    gemm_nodes<128><<<gblocks, 256, 0, stream>>>(x, W1, dis, bufA);
    aggregate<128><<<N_NODES, 64, 0, stream>>>(bufA, row_start, csr_src, dis, b1, bufB);
    gemm_nodes<64><<<gblocks, 256, 0, stream>>>(bufB, W2, dis, bufA);
    aggregate<64><<<N_NODES, 64, 0, stream>>>(bufA, row_start, csr_src, dis, b2, bufB);

    pool_graphs<<<N_GRAPHS, 64, 0, stream>>>(bufB, batch, pooled);
    bn_stats<<<1, 64, 0, stream>>>(pooled, gamma, beta, scale, shift);
    head<<<2, 256, 0, stream>>>(pooled, scale, shift, Wo1, bo1, Wo2, bo2, out);
}

// Round 4
// 521.054 us; speedup vs baseline: 1.8106x; 1.3626x over previous
//
#include <hip/hip_runtime.h>
#include <math.h>

#define N_NODES 100000
#define N_EDGES 1600000
#define N_GRAPHS 512
#define BN_EPS 1e-5f

#define SCAN_BLOCKS ((N_NODES + 1023) / 1024)   // 98

typedef unsigned int uint;
typedef unsigned short ushort;
typedef _Float16 f16;
typedef _Float16 f16x8 __attribute__((ext_vector_type(8)));
typedef float f32x4 __attribute__((ext_vector_type(4)));

// ---------------- workspace layout (bytes) ----------------
constexpr size_t OFF_CNT = 0;                 // int[N] in-degree counts
constexpr size_t OFF_ROW = 400000;            // int[N+1] CSR row starts
constexpr size_t OFF_DIS = 800128;            // float[N] rsqrt(deg+1)
constexpr size_t OFF_SC  = 1200128;           // float[64] BN scale
constexpr size_t OFF_SH  = 1200384;           // float[64] BN shift
constexpr size_t OFF_BS  = 1200640;           // int[128] scanned block sums
constexpr size_t OFF_WT  = 1201152;           // f16[128*128 + 64*128] W1^T,W2^T
constexpr size_t OFF_TK  = 1250304;           // int[E] tickets
constexpr size_t OFF_CSR = 7650304;           // int[E] CSR src indices
constexpr size_t OFF_P   = 14050304;          // 25.6MB: xs(f16) -> h1s(f16) -> h2(f32)
constexpr size_t OFF_Q   = 39650304;          // 25.6MB: M1(f16) -> M2(f16)

__device__ __forceinline__ uint packf16(float a, float b) {
    union { f16 h[2]; uint u; } z;
    z.h[0] = (f16)a; z.h[1] = (f16)b;
    return z.u;
}
__device__ __forceinline__ float2 unpackf16(uint u) {
    union { uint u; f16 h[2]; } z;
    z.u = u;
    return make_float2((float)z.h[0], (float)z.h[1]);
}

// ---------------- CSR build ----------------
__global__ void count_deg(const int* __restrict__ dst, int* __restrict__ cnt,
                          int* __restrict__ ticket) {
    int e = blockIdx.x * blockDim.x + threadIdx.x;
    if (e < N_EDGES) ticket[e] = atomicAdd(&cnt[dst[e]], 1);
}

__global__ __launch_bounds__(1024) void scan_block(const int* __restrict__ cnt,
                                                   int* __restrict__ row_start,
                                                   int* __restrict__ block_sums) {
    __shared__ int tmp[1024];
    int t = threadIdx.x;
    int i = blockIdx.x * 1024 + t;
    int v = (i < N_NODES) ? cnt[i] : 0;
    tmp[t] = v;
    __syncthreads();
    for (int off = 1; off < 1024; off <<= 1) {
        int add = (t >= off) ? tmp[t - off] : 0;
        __syncthreads();
        tmp[t] += add;
        __syncthreads();
    }
    if (i < N_NODES) row_start[i] = tmp[t];      // inclusive, block-local
    if (t == 1023) block_sums[blockIdx.x] = tmp[1023];
}

__global__ __launch_bounds__(128) void scan_tops(int* __restrict__ block_sums) {
    __shared__ int tmp[128];
    int t = threadIdx.x;
    tmp[t] = (t < SCAN_BLOCKS) ? block_sums[t] : 0;
    __syncthreads();
    for (int off = 1; off < 128; off <<= 1) {
        int add = (t >= off) ? tmp[t - off] : 0;
        __syncthreads();
        tmp[t] += add;
        __syncthreads();
    }
    block_sums[t] = tmp[t];
}

__global__ __launch_bounds__(1024) void scan_final(const int* __restrict__ cnt,
                                                   const int* __restrict__ block_sums,
                                                   int* __restrict__ row_start,
                                                   float* __restrict__ dis) {
    int t = threadIdx.x;
    int b = blockIdx.x;
    int i = b * 1024 + t;
    if (i < N_NODES) {
        int off = (b == 0) ? 0 : block_sums[b - 1];
        int c = cnt[i];
        row_start[i] = row_start[i] - c + off;   // exclusive
        dis[i] = rsqrtf((float)(c + 1));         // +1 self-loop
    }
    if (i == 0) row_start[N_NODES] = N_EDGES;
}

__global__ void scatter_csr(const int* __restrict__ src, const int* __restrict__ dst,
                            const int* __restrict__ row_start, const int* __restrict__ ticket,
                            int* __restrict__ csr_src) {
    int e = blockIdx.x * blockDim.x + threadIdx.x;
    if (e < N_EDGES) csr_src[row_start[dst[e]] + ticket[e]] = src[e];
}

// ---------------- prep: xs = f16(x * dis[n]), W^T in f16 ----------------
__global__ __launch_bounds__(256) void prep_x(const float* __restrict__ x,
                                              const float* __restrict__ dis,
                                              f16* __restrict__ xs) {
    int i = blockIdx.x * 256 + threadIdx.x;  // over N*32 float4-chunks
    if (i < N_NODES * 32) {
        int n = i >> 5;
        float d = dis[n];
        float4 v = ((const float4*)x)[i];
        uint2 p;
        p.x = packf16(v.x * d, v.y * d);
        p.y = packf16(v.z * d, v.w * d);
        ((uint2*)xs)[i] = p;
    }
}

__global__ __launch_bounds__(256) void prep_w(const float* __restrict__ W1,
                                              const float* __restrict__ W2,
                                              f16* __restrict__ wT) {
    int tid = blockIdx.x * 256 + threadIdx.x;
    if (tid < 16384) {                    // W1^T: wT[n*128+k] = W1[k*128+n]
        int n = tid >> 7, k = tid & 127;
        wT[tid] = (f16)W1[k * 128 + n];
    } else if (tid < 24576) {             // W2^T: wT[16384 + n*128+k] = W2[k*64+n]
        int t = tid - 16384;
        int n = t >> 7, k = t & 127;
        wT[tid] = (f16)W2[k * 64 + n];
    }
}

// ---------------- MFMA GEMM: Y[n,:] = f16( A[n,:] @ B ), A f16 [N][128], B^T f16 [OUTF][128] ----
template <int OUTF>
__global__ __launch_bounds__(256) void gemm_mfma(const f16* __restrict__ A,
                                                 const f16* __restrict__ Bt,
                                                 ushort* __restrict__ Y) {
    constexpr int NT = OUTF / 16;
    constexpr int PITCH = 136;            // +8 f16 pad: 2-way max bank aliasing
    __shared__ f16 sA[64 * PITCH];
    __shared__ f16 sB[OUTF * PITCH];
    int tid = threadIdx.x;
    int n0 = blockIdx.x * 64;

    for (int i = tid; i < 64 * 16; i += 256) {          // stage A: 64 rows x 256B
        int r = i >> 4, c = i & 15;
        int n = n0 + r;
        uint4 v = make_uint4(0, 0, 0, 0);
        if (n < N_NODES) v = ((const uint4*)(A + (size_t)n * 128))[c];
        *(uint4*)&sA[r * PITCH + c * 8] = v;
    }
    for (int i = tid; i < OUTF * 16; i += 256) {        // stage B^T: OUTF rows x 256B
        int r = i >> 4, c = i & 15;
        *(uint4*)&sB[r * PITCH + c * 8] = ((const uint4*)(Bt + r * 128))[c];
    }
    __syncthreads();

    int lane = tid & 63, wave = tid >> 6;
    int l15 = lane & 15, q = lane >> 4;
    int m0 = wave * 16;
    f32x4 acc[NT];
#pragma unroll
    for (int nt = 0; nt < NT; ++nt) acc[nt] = (f32x4){0.f, 0.f, 0.f, 0.f};

    const f16* pa = &sA[(m0 + l15) * PITCH + q * 8];
    const f16* pb = &sB[l15 * PITCH + q * 8];
#pragma unroll
    for (int kk = 0; kk < 4; ++kk) {
        f16x8 a = *(const f16x8*)(pa + kk * 32);
#pragma unroll
        for (int nt = 0; nt < NT; ++nt) {
            f16x8 b = *(const f16x8*)(pb + nt * 16 * PITCH + kk * 32);
            acc[nt] = __builtin_amdgcn_mfma_f32_16x16x32_f16(a, b, acc[nt], 0, 0, 0);
        }
    }

    int row_base = n0 + m0 + q * 4;                     // C/D: col=lane&15, row=q*4+reg
#pragma unroll
    for (int nt = 0; nt < NT; ++nt) {
#pragma unroll
        for (int r = 0; r < 4; ++r) {
            int row = row_base + r;
            if (row < N_NODES) {
                union { f16 h; ushort u; } z;
                z.h = (f16)acc[nt][r];
                Y[(size_t)row * OUTF + nt * 16 + l15] = z.u;
            }
        }
    }
}

// ---- aggregation L1: h1s[d] = f16( relu(dis[d]*sum M1 + b1) * dis[d] ), M1 = f16(xw*dis) ----
__global__ __launch_bounds__(64) void aggregate1(const ushort* __restrict__ M,
                                                 const int* __restrict__ row_start,
                                                 const int* __restrict__ csr_src,
                                                 const float* __restrict__ dis,
                                                 const float* __restrict__ bias,
                                                 ushort* __restrict__ H1s) {
    int n = blockIdx.x;
    int lane = threadIdx.x;
    float dn = dis[n];
    int e0 = row_start[n], e1 = row_start[n + 1];
    const uint* rows = (const uint*)M;                  // 64 uints (=128 f16) per row
    float2 t0 = unpackf16(rows[(size_t)n * 64 + lane]); // self-loop term
    float acc0 = t0.x, acc1 = t0.y;
    for (int e = e0; e < e1; ++e) {
        int s = csr_src[e];
        float2 v = unpackf16(rows[(size_t)s * 64 + lane]);
        acc0 += v.x;
        acc1 += v.y;
    }
    acc0 = fmaxf(fmaf(acc0, dn, bias[2 * lane]), 0.f) * dn;
    acc1 = fmaxf(fmaf(acc1, dn, bias[2 * lane + 1]), 0.f) * dn;
    ((uint*)H1s)[(size_t)n * 64 + lane] = packf16(acc0, acc1);
}

// ---- aggregation L2: h2[d] = relu(dis[d]*sum M2 + b2), M2 f16 [N][64], out f32 ----
__global__ __launch_bounds__(64) void aggregate2(const ushort* __restrict__ M,
                                                 const int* __restrict__ row_start,
                                                 const int* __restrict__ csr_src,
                                                 const float* __restrict__ dis,
                                                 const float* __restrict__ bias,
                                                 float* __restrict__ out) {
    int n = blockIdx.x;
    int lane = threadIdx.x;
    float dn = dis[n];
    int e0 = row_start[n], e1 = row_start[n + 1];
    const f16* rows = (const f16*)M;
    float acc = (float)rows[(size_t)n * 64 + lane];     // self-loop term
    for (int e = e0; e < e1; ++e) {
        int s = csr_src[e];
        acc += (float)rows[(size_t)s * 64 + lane];
    }
    acc = fmaf(acc, dn, bias[lane]);
    out[(size_t)n * 64 + lane] = fmaxf(acc, 0.f);
}

// ---------------- pooling ----------------
__global__ __launch_bounds__(64) void pool_graphs(const float* __restrict__ H,
                                                  const int* __restrict__ batch,
                                                  float* __restrict__ pooled) {
    int g = blockIdx.x;
    int lane = threadIdx.x;
    int lo = 0, hi = N_NODES;
    while (lo < hi) { int mid = (lo + hi) >> 1; if (batch[mid] < g) lo = mid + 1; else hi = mid; }
    int start = lo;
    hi = N_NODES;
    while (lo < hi) { int mid = (lo + hi) >> 1; if (batch[mid] < g + 1) lo = mid + 1; else hi = mid; }
    int end = lo;
    float acc = 0.f;
    for (int i = start; i < end; ++i) acc += H[(size_t)i * 64 + lane];
    pooled[g * 64 + lane] = acc;
}

// ---------------- BN batch stats -> scale/shift ----------------
__global__ __launch_bounds__(64) void bn_stats(const float* __restrict__ pooled,
                                               const float* __restrict__ gamma,
                                               const float* __restrict__ beta,
                                               float* __restrict__ scale,
                                               float* __restrict__ shift) {
    int f = threadIdx.x;
    float s = 0.f, s2 = 0.f;
    for (int g = 0; g < N_GRAPHS; ++g) {
        float v = pooled[g * 64 + f];
        s += v;
        s2 = fmaf(v, v, s2);
    }
    float mean = s * (1.0f / N_GRAPHS);
    float var = s2 * (1.0f / N_GRAPHS) - mean * mean;
    float istd = rsqrtf(var + BN_EPS);
    float sc = gamma[f] * istd;
    scale[f] = sc;
    shift[f] = beta[f] - mean * sc;
}

// ---------------- head ----------------
__global__ __launch_bounds__(256) void head(const float* __restrict__ pooled,
                                            const float* __restrict__ scale,
                                            const float* __restrict__ shift,
                                            const float* __restrict__ Wo1,
                                            const float* __restrict__ bo1,
                                            const float* __restrict__ Wo2,
                                            const float* __restrict__ bo2,
                                            float* __restrict__ out) {
    __shared__ float sW1[64 * 24];
    __shared__ float sW2[24];
    __shared__ float sb1[24];
    __shared__ float ssc[64];
    __shared__ float ssh[64];
    int tid = threadIdx.x;
    for (int i = tid; i < 64 * 24; i += 256) sW1[i] = Wo1[i];
    if (tid < 24) { sW2[tid] = Wo2[tid]; sb1[tid] = bo1[tid]; }
    if (tid < 64) { ssc[tid] = scale[tid]; ssh[tid] = shift[tid]; }
    __syncthreads();
    int g = blockIdx.x * 256 + tid;
    if (g >= N_GRAPHS) return;
    float xn[64];
    const float* pr = pooled + g * 64;
#pragma unroll
    for (int j = 0; j < 64; ++j) xn[j] = fmaf(pr[j], ssc[j], ssh[j]);
    float o = bo2[0];
#pragma unroll 4
    for (int k = 0; k < 24; ++k) {
        float h = sb1[k];
#pragma unroll
        for (int j = 0; j < 64; ++j) h = fmaf(xn[j], sW1[j * 24 + k], h);
        o = fmaf(fmaxf(h, 0.f), sW2[k], o);
    }
    out[g] = o;
}

extern "C" void kernel_launch(void* const* d_in, const int* in_sizes, int n_in,
                              void* d_out, int out_size, void* d_ws, size_t ws_size,
                              hipStream_t stream) {
    const float* x     = (const float*)d_in[0];
    const int*   ei    = (const int*)d_in[1];   // [2,E]: first E = src, next E = dst
    const int*   batch = (const int*)d_in[2];
    const float* W1    = (const float*)d_in[3];
    const float* b1    = (const float*)d_in[4];
    const float* W2    = (const float*)d_in[5];
    const float* b2    = (const float*)d_in[6];
    const float* gamma = (const float*)d_in[7];
    const float* beta  = (const float*)d_in[8];
    const float* Wo1   = (const float*)d_in[9];
    const float* bo1   = (const float*)d_in[10];
    const float* Wo2   = (const float*)d_in[11];
    const float* bo2   = (const float*)d_in[12];
    float* out = (float*)d_out;               // [512] out, then [512*64] h(=pooled)
    char* ws = (char*)d_ws;

    const int* srcv = ei;
    const int* dstv = ei + N_EDGES;
    int*    cnt      = (int*)(ws + OFF_CNT);
    int*    row_start= (int*)(ws + OFF_ROW);
    float*  dis      = (float*)(ws + OFF_DIS);
    float*  scale    = (float*)(ws + OFF_SC);
    float*  shift    = (float*)(ws + OFF_SH);
    int*    bsums    = (int*)(ws + OFF_BS);
    f16*    wT       = (f16*)(ws + OFF_WT);
    int*    ticket   = (int*)(ws + OFF_TK);
    int*    csr_src  = (int*)(ws + OFF_CSR);
    f16*    bufP     = (f16*)(ws + OFF_P);    // xs -> h1s -> h2(f32)
    ushort* bufQ     = (ushort*)(ws + OFF_Q); // M1 -> M2
    float*  pooled   = out + N_GRAPHS;        // h output region, also used downstream

    hipMemsetAsync(ws + OFF_CNT, 0, 400000, stream);

    int eblocks = (N_EDGES + 255) / 256;
    count_deg<<<eblocks, 256, 0, stream>>>(dstv, cnt, ticket);
    scan_block<<<SCAN_BLOCKS, 1024, 0, stream>>>(cnt, row_start, bsums);
    scan_tops<<<1, 128, 0, stream>>>(bsums);
    scan_final<<<SCAN_BLOCKS, 1024, 0, stream>>>(cnt, bsums, row_start, dis);
    scatter_csr<<<eblocks, 256, 0, stream>>>(srcv, dstv, row_start, ticket, csr_src);

    prep_w<<<96, 256, 0, stream>>>(W1, W2, wT);
    prep_x<<<(N_NODES * 32 + 255) / 256, 256, 0, stream>>>(x, dis, bufP);

    int gblocks = (N_NODES + 63) / 64;
    gemm_mfma<128><<<gblocks, 256, 0, stream>>>(bufP, wT, bufQ);
    aggregate1<<<N_NODES, 64, 0, stream>>>(bufQ, row_start, csr_src, dis, b1, (ushort*)bufP);
    gemm_mfma<64><<<gblocks, 256, 0, stream>>>(bufP, wT + 16384, bufQ);
    aggregate2<<<N_NODES, 64, 0, stream>>>(bufQ, row_start, csr_src, dis, b2, (float*)bufP);

    pool_graphs<<<N_GRAPHS, 64, 0, stream>>>((float*)bufP, batch, pooled);
    bn_stats<<<1, 64, 0, stream>>>(pooled, gamma, beta, scale, shift);
    head<<<2, 256, 0, stream>>>(pooled, scale, shift, Wo1, bo1, Wo2, bo2, out);
}